// Round 1
// baseline (5295.090 us; speedup 1.0000x reference)
//
#include <hip/hip_runtime.h>
#include <hip/hip_bf16.h>

typedef __bf16 bf16_t;
typedef __bf16 bf16x4 __attribute__((ext_vector_type(4)));
typedef __bf16 bf16x8 __attribute__((ext_vector_type(8)));
typedef float f32x4 __attribute__((ext_vector_type(4)));

// ---------------- prep kernels ----------------

__device__ __forceinline__ __bf16 tern1(float w) {
    // sign(round(w)), round = RNE to match jnp.round
    float r = rintf(w);
    float s = (r > 0.f) ? 1.f : ((r < 0.f) ? -1.f : 0.f);
    return (__bf16)s;
}

__global__ void ternarize_kernel(const float4* __restrict__ w, bf16x4* __restrict__ o, int n4) {
    int i = blockIdx.x * blockDim.x + threadIdx.x;
    if (i >= n4) return;
    float4 v = w[i];
    bf16x4 t = { tern1(v.x), tern1(v.y), tern1(v.z), tern1(v.w) };
    o[i] = t;
}

__global__ void cast_bf16_kernel(const float4* __restrict__ x, bf16x4* __restrict__ o, int n4) {
    int i = blockIdx.x * blockDim.x + threadIdx.x;
    if (i >= n4) return;
    float4 v = x[i];
    bf16x4 t = { (__bf16)v.x, (__bf16)v.y, (__bf16)v.z, (__bf16)v.w };
    o[i] = t;
}

// ---------------- GEMM: C[N,M] = A[N,K] @ W[M,K]^T ----------------
// m97 structure: 128x128 tile, BK=64, 4 waves (2x2), 16x16x32 bf16 MFMA,
// global_load_lds width=16 staging, linear LDS, 2 barriers / K-step.

template<bool RELU, bool OUT_BF16>
__global__ __launch_bounds__(256)
void gemm_bt_kernel(const bf16_t* __restrict__ A, const bf16_t* __restrict__ W,
                    void* __restrict__ Cout, int N, int M, int K) {
    constexpr int BK = 64;
    __shared__ __align__(16) bf16_t As[128 * BK];
    __shared__ __align__(16) bf16_t Ws[128 * BK];

    // XCD-aware bijective swizzle (all our grids are divisible by 8)
    const int nwg = gridDim.x;
    const int bid = blockIdx.x;
    const int cpx = nwg >> 3;
    const int swz = (bid & 7) * cpx + (bid >> 3);
    const int nbn = M >> 7;                    // M / 128
    const long brow = (long)(swz / nbn) << 7;  // * 128
    const long bcol = (long)(swz % nbn) << 7;

    const int tid  = threadIdx.x;
    const int lane = tid & 63;
    const int wid  = tid >> 6;   // 4 waves
    const int wr   = wid >> 1;   // wave row (0..1) -> 64 output rows
    const int wc   = wid & 1;    // wave col (0..1) -> 64 output cols

    f32x4 acc[4][4];
#pragma unroll
    for (int i = 0; i < 4; ++i)
#pragma unroll
        for (int j = 0; j < 4; ++j)
            acc[i][j] = f32x4{0.f, 0.f, 0.f, 0.f};

    // staging: per issue i (0..3), wave wid covers rows [i*32 + wid*8, +8),
    // each lane loads 8 contiguous bf16 (16B): row += lane/8, col = (lane%8)*8
    const int srow = (wid << 3) + (lane >> 3);
    const int scol = (lane & 7) << 3;
    const bf16_t* Ap = A + (brow + srow) * (long)K + scol;
    const bf16_t* Wp = W + (bcol + srow) * (long)K + scol;
    char* AsDst = (char*)As + (wid << 10);  // wave-uniform LDS base (+ lane*16 by HW)
    char* WsDst = (char*)Ws + (wid << 10);

    // fragment read base: lane reads row (sub16 index fr), k-chunk fq*8 elems
    const int fr = lane & 15;
    const int fq = lane >> 4;
    const char* ApF = (const char*)As + ((wr << 6) + fr) * 128 + (fq << 4);
    const char* WpF = (const char*)Ws + ((wc << 6) + fr) * 128 + (fq << 4);

    for (int k0 = 0; k0 < K; k0 += BK) {
#pragma unroll
        for (int i = 0; i < 4; ++i)
            __builtin_amdgcn_global_load_lds(
                (const __attribute__((address_space(1))) void*)(Ap + (long)(i * 32) * K + k0),
                (__attribute__((address_space(3))) void*)(AsDst + i * 4096),
                16, 0, 0);
#pragma unroll
        for (int i = 0; i < 4; ++i)
            __builtin_amdgcn_global_load_lds(
                (const __attribute__((address_space(1))) void*)(Wp + (long)(i * 32) * K + k0),
                (__attribute__((address_space(3))) void*)(WsDst + i * 4096),
                16, 0, 0);
        __syncthreads();  // drains vmcnt before LDS reads

#pragma unroll
        for (int kk = 0; kk < 2; ++kk) {
            bf16x8 a[4], b[4];
#pragma unroll
            for (int t = 0; t < 4; ++t)
                a[t] = *(const bf16x8*)(ApF + t * (16 * 128) + kk * 64);
#pragma unroll
            for (int t = 0; t < 4; ++t)
                b[t] = *(const bf16x8*)(WpF + t * (16 * 128) + kk * 64);
#pragma unroll
            for (int i = 0; i < 4; ++i)
#pragma unroll
                for (int j = 0; j < 4; ++j)
                    acc[i][j] = __builtin_amdgcn_mfma_f32_16x16x32_bf16(a[i], b[j], acc[i][j], 0, 0, 0);
        }
        __syncthreads();
    }

    // epilogue: C/D layout col = lane&15, row = (lane>>4)*4 + reg (m89-verified)
    const long crow0 = brow + (wr << 6) + (fq << 2);
    const long ccol0 = bcol + (wc << 6) + fr;
#pragma unroll
    for (int i = 0; i < 4; ++i)
#pragma unroll
        for (int r = 0; r < 4; ++r) {
            const long row = crow0 + i * 16 + r;
#pragma unroll
            for (int j = 0; j < 4; ++j) {
                float v = acc[i][j][r];
                if (RELU) v = fmaxf(v, 0.f);
                if (OUT_BF16)
                    ((bf16_t*)Cout)[row * M + ccol0 + j * 16] = (bf16_t)v;
                else
                    ((float*)Cout)[row * M + ccol0 + j * 16] = v;
            }
        }
}

// ---------------- launch ----------------

extern "C" void kernel_launch(void* const* d_in, const int* in_sizes, int n_in,
                              void* d_out, int out_size, void* d_ws, size_t ws_size,
                              hipStream_t stream) {
    const float* x  = (const float*)d_in[0];
    const float* W1 = (const float*)d_in[1];
    const float* W2 = (const float*)d_in[2];
    const float* W3 = (const float*)d_in[3];
    float* out = (float*)d_out;

    const long N = 16384, D0 = 2048, D1 = 8192, D2 = 8192, D3 = 2048;

    char* p = (char*)d_ws;
    bf16_t* xb  = (bf16_t*)p; p += N * D0 * 2;
    bf16_t* w1t = (bf16_t*)p; p += D1 * D0 * 2;
    bf16_t* w2t = (bf16_t*)p; p += D2 * D1 * 2;
    bf16_t* w3t = (bf16_t*)p; p += D3 * D2 * 2;
    bf16_t* h1  = (bf16_t*)p; p += N * D1 * 2;
    bf16_t* h2  = (bf16_t*)p; p += N * D2 * 2;
    // total workspace use: 768 MiB

    const int blk = 256;
    {   // x -> bf16
        int n4 = (int)(N * D0 / 4);
        cast_bf16_kernel<<<(n4 + blk - 1) / blk, blk, 0, stream>>>((const float4*)x, (bf16x4*)xb, n4);
    }
    {   // ternarize weights
        int n4 = (int)(D1 * D0 / 4);
        ternarize_kernel<<<(n4 + blk - 1) / blk, blk, 0, stream>>>((const float4*)W1, (bf16x4*)w1t, n4);
        n4 = (int)(D2 * D1 / 4);
        ternarize_kernel<<<(n4 + blk - 1) / blk, blk, 0, stream>>>((const float4*)W2, (bf16x4*)w2t, n4);
        n4 = (int)(D3 * D2 / 4);
        ternarize_kernel<<<(n4 + blk - 1) / blk, blk, 0, stream>>>((const float4*)W3, (bf16x4*)w3t, n4);
    }
    {   // L1: h1 = relu(xb @ w1t^T)   [16384, 8192]
        dim3 g((unsigned)((N >> 7) * (D1 >> 7)));
        gemm_bt_kernel<true, true><<<g, 256, 0, stream>>>(xb, w1t, (void*)h1, (int)N, (int)D1, (int)D0);
    }
    {   // L2: h2 = relu(h1 @ w2t^T)   [16384, 8192]
        dim3 g((unsigned)((N >> 7) * (D2 >> 7)));
        gemm_bt_kernel<true, true><<<g, 256, 0, stream>>>(h1, w2t, (void*)h2, (int)N, (int)D2, (int)D1);
    }
    {   // L3: out = h2 @ w3t^T        [16384, 2048] fp32
        dim3 g((unsigned)((N >> 7) * (D3 >> 7)));
        gemm_bt_kernel<false, false><<<g, 256, 0, stream>>>(h2, w3t, (void*)out, (int)N, (int)D3, (int)D2);
    }
}

// Round 3
// 3180.438 us; speedup vs baseline: 1.6649x; 1.6649x over previous
//
#include <hip/hip_runtime.h>
#include <hip/hip_bf16.h>

typedef __bf16 bf16_t;
typedef __bf16 bf16x4 __attribute__((ext_vector_type(4)));
typedef __bf16 bf16x8 __attribute__((ext_vector_type(8)));
typedef float f32x4 __attribute__((ext_vector_type(4)));

#define FENCE() asm volatile("" ::: "memory")
#define BARRIER() do { FENCE(); __builtin_amdgcn_s_barrier(); FENCE(); } while (0)

// ---------------- prep kernels ----------------

__device__ __forceinline__ __bf16 tern1(float w) {
    float r = rintf(w);  // RNE, matches jnp.round
    float s = (r > 0.f) ? 1.f : ((r < 0.f) ? -1.f : 0.f);
    return (__bf16)s;
}

__global__ void ternarize_kernel(const float4* __restrict__ w, bf16x4* __restrict__ o, int n4) {
    int i = blockIdx.x * blockDim.x + threadIdx.x;
    if (i >= n4) return;
    float4 v = w[i];
    bf16x4 t = { tern1(v.x), tern1(v.y), tern1(v.z), tern1(v.w) };
    o[i] = t;
}

__global__ void cast_bf16_kernel(const float4* __restrict__ x, bf16x4* __restrict__ o, int n4) {
    int i = blockIdx.x * blockDim.x + threadIdx.x;
    if (i >= n4) return;
    float4 v = x[i];
    bf16x4 t = { (__bf16)v.x, (__bf16)v.y, (__bf16)v.z, (__bf16)v.w };
    o[i] = t;
}

// ---------------- 256^2 8-phase GEMM: C[N,M] = A[N,K] @ W[M,K]^T ----------------
// 8 waves (2M x 4N), wave tile 128x64, BK=64, LDS 128 KiB (2 K-tile buffers).
// Per K-tile: 4 phases, each {ds_reads | 2-load half-tile stage | barrier |
// setprio(1) 16 MFMA setprio(0) | barrier}. Rolling stage: ph1->(t+1)Bh1,
// ph2->(t+2)Bh0, ph3->(t+2)Ah0, ph4->(t+2)Ah1. vmcnt(6) once per tile (ph4).
// T2 swizzle: global source pre-swizzled slot=(l&7)^(l>>3); read slot ^= row&7.

template<bool RELU, bool OUT_BF16>
__global__ __launch_bounds__(512, 2)
void gemm256_kernel(const bf16_t* __restrict__ A, const bf16_t* __restrict__ W,
                    void* __restrict__ Cout, int N, int M, int K) {
    __shared__ __align__(16) char lds[2][2][256 * 128];  // [buf][A=0/B=1][256 rows x 128B]

    // XCD-aware bijective swizzle (grids divisible by 8)
    const int nwg = gridDim.x;
    const int bid = blockIdx.x;
    const int cpx = nwg >> 3;
    const int swz = (bid & 7) * cpx + (bid >> 3);
    const int nbn = M >> 8;
    const long brow = (long)(swz / nbn) << 8;
    const long bcol = (long)(swz % nbn) << 8;

    const int tid  = threadIdx.x;
    const int lane = tid & 63;
    const int wid  = tid >> 6;   // 0..7
    const int wr   = wid >> 2;   // 0..1 -> rows wr*128..+127
    const int wc   = wid & 3;    // 0..3 -> cols wc*64..+63
    const int fr   = lane & 15;
    const int fq   = lane >> 4;

    // ---- staging addressing (per half-tile = 128 rows x 64 K = 16KB; wave stages 2x1KB chunks)
    const int s_row = (wid << 4) + (lane >> 3);          // 0..127 within half
    const int s_col = ((lane & 7) ^ (lane >> 3)) << 3;   // pre-swizzled source col (elems)
    const bf16_t* Ast = A + (brow + s_row) * (long)K + s_col;
    const bf16_t* Wst = W + (bcol + s_row) * (long)K + s_col;

    // ---- fragment read addressing: byte = row*128 + ((kk*4+fq)^(row&7))*16, row&7 == fr&7
    const unsigned abase = ((unsigned)(wr * 128 + fr) << 7) | ((unsigned)(fq ^ (fr & 7)) << 4);
    const unsigned bbase = ((unsigned)(wc *  64 + fr) << 7) | ((unsigned)(fq ^ (fr & 7)) << 4);

    const int NT = K >> 6;

    f32x4 acc[8][4];
#pragma unroll
    for (int i = 0; i < 8; ++i)
#pragma unroll
        for (int j = 0; j < 4; ++j)
            acc[i][j] = f32x4{0.f, 0.f, 0.f, 0.f};

    auto stage = [&](int tt, int ab, int h) {
        const bf16_t* s = (ab ? Wst : Ast) + (long)h * 128 * K + (long)tt * 64;
        char* d = &lds[tt & 1][ab][0] + (h << 14) + (wid << 11);
        __builtin_amdgcn_global_load_lds((const __attribute__((address_space(1))) void*)s,
                                         (__attribute__((address_space(3))) void*)d, 16, 0, 0);
        __builtin_amdgcn_global_load_lds((const __attribute__((address_space(1))) void*)(s + 8L * K),
                                         (__attribute__((address_space(3))) void*)(d + 1024), 16, 0, 0);
    };

    // ---- prologue: tile0 all 4 halves, tile1 {Bh0, Ah0, Ah1}; t1:Bh1 comes at t0.ph1
    stage(0, 0, 0); stage(0, 0, 1); stage(0, 1, 0); stage(0, 1, 1);
    if (NT > 1) { stage(1, 1, 0); stage(1, 0, 0); stage(1, 0, 1); }
    asm volatile("s_waitcnt vmcnt(6)" ::: "memory");   // tile0 landed; t1's 3 halves in flight
    BARRIER();

    for (int t = 0; t < NT; ++t) {
        const char* Ar = &lds[t & 1][0][0];
        const char* Br = &lds[t & 1][1][0];
        bf16x8 a[8][2], b[4][2];

        // ===== phase 1: read all B (8) + A i0-3 (8); stage (t+1):Bh1; MFMA q1 (i0-3 x j0-1)
#pragma unroll
        for (int i = 0; i < 4; ++i)
#pragma unroll
            for (int kk = 0; kk < 2; ++kk)
                a[i][kk] = *(const bf16x8*)(Ar + ((abase + (unsigned)i * 2048u) ^ (unsigned)(kk << 6)));
#pragma unroll
        for (int j = 0; j < 4; ++j)
#pragma unroll
            for (int kk = 0; kk < 2; ++kk)
                b[j][kk] = *(const bf16x8*)(Br + ((bbase + (unsigned)j * 2048u) ^ (unsigned)(kk << 6)));
        if (t + 1 < NT) stage(t + 1, 1, 1);
        BARRIER();
        __builtin_amdgcn_s_setprio(1);
#pragma unroll
        for (int kk = 0; kk < 2; ++kk)
#pragma unroll
            for (int i = 0; i < 4; ++i)
#pragma unroll
                for (int j = 0; j < 2; ++j)
                    acc[i][j] = __builtin_amdgcn_mfma_f32_16x16x32_bf16(a[i][kk], b[j][kk], acc[i][j], 0, 0, 0);
        __builtin_amdgcn_s_setprio(0);
        asm volatile("s_waitcnt lgkmcnt(0)" ::: "memory");  // all my ds_reads done before next overwrite-issue
        BARRIER();

        // ===== phase 2: read A i4-7 (8); stage (t+2):Bh0; MFMA q2 (i0-3 x j2-3)
#pragma unroll
        for (int i = 4; i < 8; ++i)
#pragma unroll
            for (int kk = 0; kk < 2; ++kk)
                a[i][kk] = *(const bf16x8*)(Ar + ((abase + (unsigned)i * 2048u) ^ (unsigned)(kk << 6)));
        if (t + 2 < NT) stage(t + 2, 1, 0);
        BARRIER();
        __builtin_amdgcn_s_setprio(1);
#pragma unroll
        for (int kk = 0; kk < 2; ++kk)
#pragma unroll
            for (int i = 0; i < 4; ++i)
#pragma unroll
                for (int j = 2; j < 4; ++j)
                    acc[i][j] = __builtin_amdgcn_mfma_f32_16x16x32_bf16(a[i][kk], b[j][kk], acc[i][j], 0, 0, 0);
        __builtin_amdgcn_s_setprio(0);
        asm volatile("s_waitcnt lgkmcnt(0)" ::: "memory");
        BARRIER();

        // ===== phase 3: stage (t+2):Ah0; MFMA q3 (i4-7 x j0-1)
        if (t + 2 < NT) stage(t + 2, 0, 0);
        BARRIER();
        __builtin_amdgcn_s_setprio(1);
#pragma unroll
        for (int kk = 0; kk < 2; ++kk)
#pragma unroll
            for (int i = 4; i < 8; ++i)
#pragma unroll
                for (int j = 0; j < 2; ++j)
                    acc[i][j] = __builtin_amdgcn_mfma_f32_16x16x32_bf16(a[i][kk], b[j][kk], acc[i][j], 0, 0, 0);
        __builtin_amdgcn_s_setprio(0);
        BARRIER();

        // ===== phase 4: stage (t+2):Ah1; MFMA q4 (i4-7 x j2-3); vmcnt(6); barrier
        if (t + 2 < NT) stage(t + 2, 0, 1);
        BARRIER();
        __builtin_amdgcn_s_setprio(1);
#pragma unroll
        for (int kk = 0; kk < 2; ++kk)
#pragma unroll
            for (int i = 4; i < 8; ++i)
#pragma unroll
                for (int j = 2; j < 4; ++j)
                    acc[i][j] = __builtin_amdgcn_mfma_f32_16x16x32_bf16(a[i][kk], b[j][kk], acc[i][j], 0, 0, 0);
        __builtin_amdgcn_s_setprio(0);
        if (t + 2 < NT) asm volatile("s_waitcnt vmcnt(6)" ::: "memory");  // (t+1) fully landed
        else            asm volatile("s_waitcnt vmcnt(0)" ::: "memory");  // epilogue drain
        BARRIER();
    }

    // ---- epilogue: C/D layout col = lane&15, row = (lane>>4)*4 + reg
    const long crow0 = brow + wr * 128 + (fq << 2);
    const long ccol0 = bcol + wc * 64 + fr;
#pragma unroll
    for (int i = 0; i < 8; ++i)
#pragma unroll
        for (int r = 0; r < 4; ++r) {
            const long row = crow0 + i * 16 + r;
#pragma unroll
            for (int j = 0; j < 4; ++j) {
                float v = acc[i][j][r];
                if (RELU) v = fmaxf(v, 0.f);
                if (OUT_BF16)
                    ((bf16_t*)Cout)[row * M + ccol0 + j * 16] = (bf16_t)v;
                else
                    ((float*)Cout)[row * M + ccol0 + j * 16] = v;
            }
        }
}

// ---------------- launch ----------------

extern "C" void kernel_launch(void* const* d_in, const int* in_sizes, int n_in,
                              void* d_out, int out_size, void* d_ws, size_t ws_size,
                              hipStream_t stream) {
    const float* x  = (const float*)d_in[0];
    const float* W1 = (const float*)d_in[1];
    const float* W2 = (const float*)d_in[2];
    const float* W3 = (const float*)d_in[3];
    float* out = (float*)d_out;

    const long N = 16384, D0 = 2048, D1 = 8192, D2 = 8192, D3 = 2048;

    char* p = (char*)d_ws;
    bf16_t* xb  = (bf16_t*)p; p += N * D0 * 2;
    bf16_t* w1t = (bf16_t*)p; p += D1 * D0 * 2;
    bf16_t* w2t = (bf16_t*)p; p += D2 * D1 * 2;
    bf16_t* w3t = (bf16_t*)p; p += D3 * D2 * 2;
    bf16_t* h1  = (bf16_t*)p; p += N * D1 * 2;
    bf16_t* h2  = (bf16_t*)p; p += N * D2 * 2;

    const int blk = 256;
    {   // x -> bf16
        int n4 = (int)(N * D0 / 4);
        cast_bf16_kernel<<<(n4 + blk - 1) / blk, blk, 0, stream>>>((const float4*)x, (bf16x4*)xb, n4);
    }
    {   // ternarize weights
        int n4 = (int)(D1 * D0 / 4);
        ternarize_kernel<<<(n4 + blk - 1) / blk, blk, 0, stream>>>((const float4*)W1, (bf16x4*)w1t, n4);
        n4 = (int)(D2 * D1 / 4);
        ternarize_kernel<<<(n4 + blk - 1) / blk, blk, 0, stream>>>((const float4*)W2, (bf16x4*)w2t, n4);
        n4 = (int)(D3 * D2 / 4);
        ternarize_kernel<<<(n4 + blk - 1) / blk, blk, 0, stream>>>((const float4*)W3, (bf16x4*)w3t, n4);
    }
    {   // L1: h1 = relu(xb @ w1t^T)   [16384, 8192]
        dim3 g((unsigned)((N >> 8) * (D1 >> 8)));
        gemm256_kernel<true, true><<<g, 512, 0, stream>>>(xb, w1t, (void*)h1, (int)N, (int)D1, (int)D0);
    }
    {   // L2: h2 = relu(h1 @ w2t^T)   [16384, 8192]
        dim3 g((unsigned)((N >> 8) * (D2 >> 8)));
        gemm256_kernel<true, true><<<g, 512, 0, stream>>>(h1, w2t, (void*)h2, (int)N, (int)D2, (int)D1);
    }
    {   // L3: out = h2 @ w3t^T        [16384, 2048] fp32
        dim3 g((unsigned)((N >> 8) * (D3 >> 8)));
        gemm256_kernel<false, false><<<g, 512, 0, stream>>>(h2, w3t, (void*)out, (int)N, (int)D3, (int)D2);
    }
}